// Round 1
// baseline (612.309 us; speedup 1.0000x reference)
//
#include <hip/hip_runtime.h>
#include <hip/hip_bf16.h>

typedef unsigned short u16;
typedef unsigned int   u32;
typedef short bf16x8 __attribute__((ext_vector_type(8)));
typedef float f32x4  __attribute__((ext_vector_type(4)));

#define O_N    4
#define D_K    128
#define D_V    512
#define BANK   7200
#define NQ     3600
#define NT     64            // query columns per block
#define BT     32            // banks per iteration
#define NTILES 57            // ceil(3600/64); 57*8 = 456 blocks exactly
#define ITERS  (BANK/BT)     // 225
#define VH_ROWS 256          // v rows per block (half of 512)

// ---- LDS layout (bytes). All tiles stored "linear layout + XOR swizzle on
// 16B granule", applied identically on write and read (rule: both-sides).
#define K_OFF    0           // K tile  [32 b][128 d] bf16, row 256B, g ^= (b&7)   (8192)
#define V_OFF    8192        // V tile  [256 v][32 b] bf16, row 64B,  g ^= key4(v) (16384)
#define P_OFF    24576       // P tile  [64 n][32 b]  bf16, row padded to 128B, g ^= (n&7) (8192)
#define MASK_OFF 32768       // 32 f32 (128)
#define LMM_OFF  32896       // l[64], mm[64] f32 (512)
#define SMEM_BYTES 33408
#define Q_OFF    V_OFF       // Q tile [64 n][128 d] bf16, row 256B, g ^= (n&7); prologue only

static __device__ __forceinline__ u16 f2bf(float x) {
    // round-to-nearest-even f32 -> bf16 (finite inputs)
    u32 u = __builtin_bit_cast(u32, x);
    return (u16)((u + 0x7FFFu + ((u >> 16) & 1u)) >> 16);
}

// ---------------- preconv kernels ----------------

// keys f32 [O][128][7200] -> bf16 [O][7200][128] (transpose so contraction dim d
// is contiguous for the streamed K operand)
__global__ void k_transpose_bf16(const float* __restrict__ in, u16* __restrict__ out) {
    __shared__ float tile[32][33];
    const int obj = blockIdx.z;
    const float* src = in + (size_t)obj * D_K * BANK;
    u16* dst = out + (size_t)obj * BANK * D_K;
    const int bx = blockIdx.x * 32;   // bank
    const int by = blockIdx.y * 32;   // d
    const int tx = threadIdx.x, ty = threadIdx.y;  // 32 x 8
#pragma unroll
    for (int i = 0; i < 4; i++)
        tile[ty + 8 * i][tx] = src[(size_t)(by + ty + 8 * i) * BANK + bx + tx];
    __syncthreads();
#pragma unroll
    for (int i = 0; i < 4; i++)
        dst[(size_t)(bx + ty + 8 * i) * D_K + by + tx] = f2bf(tile[tx][ty + 8 * i]);
}

// values f32 -> bf16, linear
__global__ void k_convert_bf16(const float* __restrict__ in, u16* __restrict__ out, int n4) {
    int idx = blockIdx.x * blockDim.x + threadIdx.x;
    int stride = gridDim.x * blockDim.x;
    for (int i = idx; i < n4; i += stride) {
        float4 v = reinterpret_cast<const float4*>(in)[i];
        ushort4 o;
        o.x = f2bf(v.x); o.y = f2bf(v.y); o.z = f2bf(v.z); o.w = f2bf(v.w);
        reinterpret_cast<ushort4*>(out)[i] = o;
    }
}

__global__ void k_zero(float* out, int n) {
    int i = blockIdx.x * blockDim.x + threadIdx.x;
    if (i < n) out[i] = 0.f;
}

// ---------------- main fused kernel ----------------
// Block: (object o, 64-query tile, v-half vh). 4 waves / 256 threads.
// blockIdx.x = tile*8 + (o*2+vh)  -> consecutive blocks of one (o,vh) group
// land on one XCD (blockIdx%8 round-robin), so the group's K + V-half slice
// (~5.5 MB bf16) stays in that XCD's L2.
__launch_bounds__(256, 2)
__global__ void k_matcher(const u16* __restrict__ Kt,     // [O][7200][128] bf16
                          const u16* __restrict__ Vb,     // [O][512][7200] bf16
                          const float* __restrict__ masks,// [O][7200]
                          const float* __restrict__ q_in, // [128][3600]
                          const float* __restrict__ q_out,// [512][3600]
                          float* __restrict__ out)        // [O][1024][3600]
{
    __shared__ __align__(16) char smem[SMEM_BYTES];
    const int tid  = threadIdx.x;
    const int wave = tid >> 6;
    const int lane = tid & 63;
    const int q    = lane >> 4;   // quad index 0..3
    const int lr   = lane & 15;   // lane-row 0..15

    const int grp  = blockIdx.x & 7;
    const int o    = grp >> 1;
    const int vh   = grp & 1;
    const int n0   = (blockIdx.x >> 3) * NT;

    // ---- stage Q tile: Q_lds[n][d] bf16, granule swizzle ^ (n&7)
    for (int idx = tid; idx < NT * D_K; idx += 256) {
        int d = idx >> 6;         // 0..127 (64 consecutive n per step: coalesced)
        int n = idx & 63;
        int gn = n0 + n;
        float v = (gn < NQ) ? q_in[(size_t)d * NQ + gn] : 0.f;
        int bb = d * 2;                       // byte in row (pre-swizzle)
        int sb = n * 256 + ((((bb >> 4) ^ (n & 7)) << 4) | (bb & 15));
        *reinterpret_cast<u16*>(smem + Q_OFF + sb) = f2bf(v);
    }
    __syncthreads();

    // ---- Q fragments for this wave's 16 columns (n = 16*wave + lr)
    bf16x8 qf[4];
    {
        const int n = 16 * wave + lr;
#pragma unroll
        for (int ds = 0; ds < 4; ds++) {
            int g = (4 * ds + q) ^ (n & 7);
            qf[ds] = *reinterpret_cast<const bf16x8*>(smem + Q_OFF + n * 256 + g * 16);
        }
    }
    __syncthreads();   // Q region about to be reused as V tile

    const f32x4 zero4 = {0.f, 0.f, 0.f, 0.f};
    f32x4 acc[4][4];
#pragma unroll
    for (int i = 0; i < 4; i++)
#pragma unroll
        for (int j = 0; j < 4; j++) acc[i][j] = zero4;
    float l_part = 0.f, mm_part = 0.f;
    const float scale = 0.08838834764831845f;  // 1/sqrt(128)

    const u16*  Ko = Kt + (size_t)o * BANK * D_K;
    const u16*  Vo = Vb + (size_t)o * D_V * BANK + (size_t)vh * VH_ROWS * BANK;
    const float* Mo = masks + (size_t)o * BANK;

    for (int it = 0; it < ITERS; it++) {
        const int b0 = it * BT;
        // ---- stage K tile: 512 x 16B granules, linear global read, swizzled LDS write
#pragma unroll
        for (int k = 0; k < 2; k++) {
            int s = tid + k * 256;
            int b = s >> 4, g = s & 15;
            uint4 val = *reinterpret_cast<const uint4*>(Ko + (size_t)(b0 + b) * D_K + g * 8);
            *reinterpret_cast<uint4*>(smem + K_OFF + b * 256 + ((g ^ (b & 7)) << 4)) = val;
        }
        // ---- stage V tile: 1024 x 16B granules
#pragma unroll
        for (int k = 0; k < 4; k++) {
            int s = tid + k * 256;
            int v = s >> 2, g = s & 3;
            uint4 val = *reinterpret_cast<const uint4*>(Vo + (size_t)v * BANK + b0 + g * 8);
            int key = (v ^ (v >> 2)) & 3;
            *reinterpret_cast<uint4*>(smem + V_OFF + v * 64 + ((g ^ key) << 4)) = val;
        }
        if (tid < BT)
            *reinterpret_cast<float*>(smem + MASK_OFF + tid * 4) = Mo[b0 + tid];
        __syncthreads();

        // ---- QK^T for this wave's 16 columns; softmax terms; P -> LDS
#pragma unroll
        for (int t = 0; t < 2; t++) {
            f32x4 s_acc = zero4;
            const int b_r = 16 * t + lr;        // S-tile row (bank within tile)
#pragma unroll
            for (int ds = 0; ds < 4; ds++) {
                int g = (4 * ds + q) ^ (lr & 7);   // (b_r&7)==(lr&7)
                bf16x8 kf = *reinterpret_cast<const bf16x8*>(smem + K_OFF + b_r * 256 + g * 16);
                s_acc = __builtin_amdgcn_mfma_f32_16x16x32_bf16(kf, qf[ds], s_acc, 0, 0, 0);
            }
            // C/D layout: col n = 16*wave+lr, row b = 16*t + 4*q + r
            float4 mv = *reinterpret_cast<const float4*>(smem + MASK_OFF + (16 * t + 4 * q) * 4);
            float p0 = __expf(s_acc[0] * scale);
            float p1 = __expf(s_acc[1] * scale);
            float p2 = __expf(s_acc[2] * scale);
            float p3 = __expf(s_acc[3] * scale);
            l_part  += p0 + p1 + p2 + p3;
            mm_part += p0 * mv.x + p1 * mv.y + p2 * mv.z + p3 * mv.w;
            ushort4 pk;
            pk.x = f2bf(p0); pk.y = f2bf(p1); pk.z = f2bf(p2); pk.w = f2bf(p3);
            const int n = 16 * wave + lr;
            int g = (2 * t + (q >> 1)) ^ (n & 7);
            *reinterpret_cast<ushort4*>(smem + P_OFF + n * 128 + g * 16 + (q & 1) * 8) = pk;
        }
        __syncthreads();

        // ---- PV: this wave owns v_local = [64*wave, 64*wave+64)
        bf16x8 pf[4];
#pragma unroll
        for (int ng = 0; ng < 4; ng++) {
            int n = 16 * ng + lr;
            int g = q ^ (n & 7);
            pf[ng] = *reinterpret_cast<const bf16x8*>(smem + P_OFF + n * 128 + g * 16);
        }
#pragma unroll
        for (int vt = 0; vt < 4; vt++) {
            int v = 64 * wave + 16 * vt + lr;
            int key = (v ^ (v >> 2)) & 3;
            int g = q ^ key;
            bf16x8 vf = *reinterpret_cast<const bf16x8*>(smem + V_OFF + v * 64 + g * 16);
#pragma unroll
            for (int ng = 0; ng < 4; ng++)
                acc[vt][ng] = __builtin_amdgcn_mfma_f32_16x16x32_bf16(vf, pf[ng], acc[vt][ng], 0, 0, 0);
        }
        __syncthreads();
    }

    // ---- finalize l, mm: sum the 4 lanes holding each column
    l_part  += __shfl_xor(l_part, 16);  l_part  += __shfl_xor(l_part, 32);
    mm_part += __shfl_xor(mm_part, 16); mm_part += __shfl_xor(mm_part, 32);
    float* l_lds  = reinterpret_cast<float*>(smem + LMM_OFF);
    float* mm_lds = l_lds + 64;
    if (lane < 16) {
        l_lds[16 * wave + lr]  = l_part;
        mm_lds[16 * wave + lr] = mm_part;
    }
    __syncthreads();

    // ---- epilogue: mem = acc/l ; gated = q_out * (mm/l)
    float* outo = out + (size_t)o * (1024 * NQ);
#pragma unroll
    for (int ng = 0; ng < 4; ng++) {
        const int n  = 16 * ng + lr;
        const int gn = n0 + n;
        if (gn >= NQ) continue;
        const float invl = 1.f / l_lds[n];
        const float gate = mm_lds[n] * invl;
#pragma unroll
        for (int vt = 0; vt < 4; vt++) {
#pragma unroll
            for (int r = 0; r < 4; r++) {
                const int v = vh * VH_ROWS + 64 * wave + 16 * vt + 4 * q + r;
                outo[(size_t)v * NQ + gn] = acc[vt][ng][r] * invl;
                outo[(size_t)(512 + v) * NQ + gn] = q_out[(size_t)v * NQ + gn] * gate;
            }
        }
    }
}

extern "C" void kernel_launch(void* const* d_in, const int* in_sizes, int n_in,
                              void* d_out, int out_size, void* d_ws, size_t ws_size,
                              hipStream_t stream) {
    const float* keys   = (const float*)d_in[0];
    const float* values = (const float*)d_in[1];
    const float* masks  = (const float*)d_in[2];
    const float* q_in   = (const float*)d_in[3];
    const float* q_outp = (const float*)d_in[4];
    float* out = (float*)d_out;

    const size_t K_BYTES = (size_t)O_N * BANK * D_K * 2;   //  7,372,800
    const size_t V_BYTES = (size_t)O_N * D_V * BANK * 2;   // 29,491,200
    if (ws_size < K_BYTES + V_BYTES) {
        // sentinel: zero output (diagnosable: absmax == max|ref|, tiny duration)
        k_zero<<<(out_size + 255) / 256, 256, 0, stream>>>(out, out_size);
        return;
    }
    u16* Kt = (u16*)d_ws;
    u16* Vb = (u16*)((char*)d_ws + K_BYTES);

    dim3 tb(32, 8);
    dim3 tg(BANK / 32, D_K / 32, O_N);
    k_transpose_bf16<<<tg, tb, 0, stream>>>(keys, Kt);

    const int n4 = O_N * D_V * BANK / 4;
    k_convert_bf16<<<2048, 256, 0, stream>>>(values, Vb, n4);

    k_matcher<<<NTILES * 8, 256, 0, stream>>>(Kt, Vb, masks, q_in, q_outp, out);
}

// Round 2
// 325.673 us; speedup vs baseline: 1.8801x; 1.8801x over previous
//
#include <hip/hip_runtime.h>
#include <hip/hip_bf16.h>

typedef unsigned short u16;
typedef unsigned int   u32;
typedef short bf16x8 __attribute__((ext_vector_type(8)));
typedef float f32x4  __attribute__((ext_vector_type(4)));

#define O_N    4
#define D_K    128
#define D_V    512
#define BANK   7200
#define NQ     3600
#define NT     64            // query columns per block
#define BT     32            // banks per iteration
#define NTILES 57            // ceil(3600/64)
#define ITERS  (BANK/BT)     // 225
#define VH_ROWS 256          // v rows per block (half of 512)

// ---- LDS layout (bytes)
#define K_OFF    0           // K dbuf: 2 x [32 b][128 d] bf16 (2 x 8192)
#define V_OFF    16384       // V dbuf: 2 x [256 v][32 b] bf16 (2 x 16384)
#define P_OFF    49152       // P tile [64 n][32 b] bf16, 64B rows (4096)
#define LMM_OFF  53248       // l[64], mm[64] f32 (512)
#define SMEM_BYTES 53760
#define Q_OFF    V_OFF       // Q tile [64 n][128 d] bf16 (16KB), prologue only

// global_load_lds: linear LDS dest (wave base + lane*16); source address is
// pre-permuted per-lane so the READ-side swizzle formulas keep working.
#define GLL(gsrc, ldst) __builtin_amdgcn_global_load_lds( \
    (const __attribute__((address_space(1))) void*)(gsrc), \
    (__attribute__((address_space(3))) void*)(ldst), 16, 0, 0)

static __device__ __forceinline__ u16 f2bf(float x) {
    u32 u = __builtin_bit_cast(u32, x);
    return (u16)((u + 0x7FFFu + ((u >> 16) & 1u)) >> 16);
}

// ---------------- preconv kernels ----------------

__global__ void k_transpose_bf16(const float* __restrict__ in, u16* __restrict__ out) {
    __shared__ float tile[32][33];
    const int obj = blockIdx.z;
    const float* src = in + (size_t)obj * D_K * BANK;
    u16* dst = out + (size_t)obj * BANK * D_K;
    const int bx = blockIdx.x * 32;   // bank
    const int by = blockIdx.y * 32;   // d
    const int tx = threadIdx.x, ty = threadIdx.y;  // 32 x 8
#pragma unroll
    for (int i = 0; i < 4; i++)
        tile[ty + 8 * i][tx] = src[(size_t)(by + ty + 8 * i) * BANK + bx + tx];
    __syncthreads();
#pragma unroll
    for (int i = 0; i < 4; i++)
        dst[(size_t)(bx + ty + 8 * i) * D_K + by + tx] = f2bf(tile[tx][ty + 8 * i]);
}

__global__ void k_convert_bf16(const float* __restrict__ in, u16* __restrict__ out, int n4) {
    int idx = blockIdx.x * blockDim.x + threadIdx.x;
    int stride = gridDim.x * blockDim.x;
    for (int i = idx; i < n4; i += stride) {
        float4 v = reinterpret_cast<const float4*>(in)[i];
        ushort4 o;
        o.x = f2bf(v.x); o.y = f2bf(v.y); o.z = f2bf(v.z); o.w = f2bf(v.w);
        reinterpret_cast<ushort4*>(out)[i] = o;
    }
}

__global__ void k_zero(float* out, int n) {
    int i = blockIdx.x * blockDim.x + threadIdx.x;
    if (i < n) out[i] = 0.f;
}

// ---------------- main fused kernel ----------------
// blockIdx.x = ((tile*G + g) << 3) | (o*2+vh): (o,vh) pinned per XCD for L2.
__launch_bounds__(256, 3)
__global__ void k_matcher(const u16* __restrict__ Kt,     // [O][7200][128] bf16
                          const u16* __restrict__ Vb,     // [O][512][7200] bf16
                          const float* __restrict__ masks,// [O][7200]
                          const float* __restrict__ q_in, // [128][3600]
                          const float* __restrict__ q_out,// [512][3600]
                          float* __restrict__ out,        // [O][1024][3600]
                          int G, float* __restrict__ lw, float* __restrict__ mw)
{
    __shared__ __align__(16) char smem[SMEM_BYTES];
    const int tid  = threadIdx.x;
    const int wave = tid >> 6;
    const int lane = tid & 63;
    const int q    = lane >> 4;
    const int lr   = lane & 15;

    const int grp  = blockIdx.x & 7;
    const int o    = grp >> 1;
    const int vh   = grp & 1;
    const int rest = blockIdx.x >> 3;
    const int tile = rest / G;
    const int g    = rest - tile * G;
    const int n0   = tile * NT;
    const int it0  = (ITERS * g) / G;
    const int it1  = (ITERS * (g + 1)) / G;
    const int nit  = it1 - it0;

    // ---- stage Q tile: Q_lds[n][d] bf16, granule swizzle ^ (n&7)
    for (int idx = tid; idx < NT * D_K; idx += 256) {
        int d = idx >> 6;
        int n = idx & 63;
        int gn = n0 + n;
        float v = (gn < NQ) ? q_in[(size_t)d * NQ + gn] : 0.f;
        int bb = d * 2;
        int sb = n * 256 + ((((bb >> 4) ^ (n & 7)) << 4) | (bb & 15));
        *reinterpret_cast<u16*>(smem + Q_OFF + sb) = f2bf(v);
    }
    __syncthreads();

    bf16x8 qf[4];
    {
        const int n = 16 * wave + lr;
#pragma unroll
        for (int ds = 0; ds < 4; ds++) {
            int gq = (4 * ds + q) ^ (n & 7);
            qf[ds] = *reinterpret_cast<const bf16x8*>(smem + Q_OFF + n * 256 + gq * 16);
        }
    }
    __syncthreads();   // Q region about to be overwritten by V staging

    const f32x4 zero4 = {0.f, 0.f, 0.f, 0.f};
    f32x4 acc[4][4];
#pragma unroll
    for (int i = 0; i < 4; i++)
#pragma unroll
        for (int j = 0; j < 4; j++) acc[i][j] = zero4;
    float l_part = 0.f, mm_part = 0.f;
    const float scale = 0.08838834764831845f;  // 1/sqrt(128)

    const u16* Ko = Kt + (size_t)o * BANK * D_K;
    const u16* Vo = Vb + (size_t)o * D_V * BANK + (size_t)vh * VH_ROWS * BANK;
    const float* mPtr = masks + (size_t)o * BANK + it0 * BT + 4 * q;

    // ---- gll source pointers (pre-permuted so linear LDS dest == swizzled content)
    // K slot s: b=s>>4, content granule = (s&15)^(b&7)
    const int sK0 = tid, sK1 = tid + 256;
    const u16* kSrc0 = Ko + (size_t)(it0 * BT + (sK0 >> 4)) * D_K + (((sK0 & 15) ^ ((sK0 >> 4) & 7)) << 3);
    const u16* kSrc1 = Ko + (size_t)(it0 * BT + (sK1 >> 4)) * D_K + (((sK1 & 15) ^ ((sK1 >> 4) & 7)) << 3);
    // V slot s: v=s>>2, content granule = (s&3)^key(v), key=(v^(v>>2))&3
#define VSRC(k)  (Vo + (size_t)((tid + (k)*256) >> 2) * BANK + it0 * BT \
                  + ((((tid + (k)*256) & 3) ^ ((((tid + (k)*256) >> 2) ^ ((tid + (k)*256) >> 4)) & 3)) << 3))
    const u16* vSrc0 = VSRC(0);
    const u16* vSrc1 = VSRC(1);
    const u16* vSrc2 = VSRC(2);
    const u16* vSrc3 = VSRC(3);
#undef VSRC

#define ISSUE_STAGE(buf) do {                                              \
        char* kb_ = smem + K_OFF + (buf) * 8192 + wave * 1024;             \
        GLL(kSrc0, kb_);                                                   \
        GLL(kSrc1, kb_ + 4096);                                            \
        char* vb_ = smem + V_OFF + (buf) * 16384 + wave * 1024;            \
        GLL(vSrc0, vb_);                                                   \
        GLL(vSrc1, vb_ + 4096);                                            \
        GLL(vSrc2, vb_ + 8192);                                            \
        GLL(vSrc3, vb_ + 12288);                                           \
        kSrc0 += BT * D_K; kSrc1 += BT * D_K;                              \
        vSrc0 += BT; vSrc1 += BT; vSrc2 += BT; vSrc3 += BT;                \
    } while (0)

    ISSUE_STAGE(0);

    for (int ii = 0; ii < nit; ii++) {
        const int cur = ii & 1;
        // ---- start fence: my gll for buf[cur] done; all waves past prev iter
        asm volatile("s_waitcnt vmcnt(0)" ::: "memory");
        __builtin_amdgcn_s_barrier();
        __builtin_amdgcn_sched_barrier(0);
        if (ii + 1 < nit) ISSUE_STAGE(cur ^ 1);

        // ---- QK^T for this wave's 16 columns; softmax terms; P -> LDS
        const char* kb = smem + K_OFF + cur * 8192;
#pragma unroll
        for (int t = 0; t < 2; t++) {
            f32x4 s_acc = zero4;
            const int b_r = 16 * t + lr;
#pragma unroll
            for (int ds = 0; ds < 4; ds++) {
                int gk = (4 * ds + q) ^ (lr & 7);
                bf16x8 kf = *reinterpret_cast<const bf16x8*>(kb + b_r * 256 + gk * 16);
                s_acc = __builtin_amdgcn_mfma_f32_16x16x32_bf16(kf, qf[ds], s_acc, 0, 0, 0);
            }
            float4 mv = *reinterpret_cast<const float4*>(mPtr + 16 * t);
            float p0 = __expf(s_acc[0] * scale);
            float p1 = __expf(s_acc[1] * scale);
            float p2 = __expf(s_acc[2] * scale);
            float p3 = __expf(s_acc[3] * scale);
            l_part  += p0 + p1 + p2 + p3;
            mm_part += p0 * mv.x + p1 * mv.y + p2 * mv.z + p3 * mv.w;
            ushort4 pk;
            pk.x = f2bf(p0); pk.y = f2bf(p1); pk.z = f2bf(p2); pk.w = f2bf(p3);
            const int n = 16 * wave + lr;
            int gp = (2 * t + (q >> 1)) ^ (n & 3);
            *reinterpret_cast<ushort4*>(smem + P_OFF + n * 64 + gp * 16 + (q & 1) * 8) = pk;
        }
        mPtr += BT;

        // ---- mid fence: P visible to all waves (LDS only; gll stays in flight)
        asm volatile("s_waitcnt lgkmcnt(0)" ::: "memory");
        __builtin_amdgcn_s_barrier();
        __builtin_amdgcn_sched_barrier(0);

        // ---- PV: this wave owns v_local = [64*wave, 64*wave+64)
        const char* vb = smem + V_OFF + cur * 16384;
        bf16x8 pf[4];
#pragma unroll
        for (int ng = 0; ng < 4; ng++) {
            int n = 16 * ng + lr;
            pf[ng] = *reinterpret_cast<const bf16x8*>(smem + P_OFF + n * 64 + ((q ^ (n & 3)) << 4));
        }
#pragma unroll
        for (int vt = 0; vt < 4; vt++) {
            int v = 64 * wave + 16 * vt + lr;
            int key = (v ^ (v >> 2)) & 3;
            bf16x8 vf = *reinterpret_cast<const bf16x8*>(vb + v * 64 + ((q ^ key) << 4));
#pragma unroll
            for (int ng = 0; ng < 4; ng++)
                acc[vt][ng] = __builtin_amdgcn_mfma_f32_16x16x32_bf16(vf, pf[ng], acc[vt][ng], 0, 0, 0);
        }
    }

    // ---- finalize l, mm
    l_part  += __shfl_xor(l_part, 16);  l_part  += __shfl_xor(l_part, 32);
    mm_part += __shfl_xor(mm_part, 16); mm_part += __shfl_xor(mm_part, 32);
    float* l_lds  = reinterpret_cast<float*>(smem + LMM_OFF);
    float* mm_lds = l_lds + 64;
    if (lane < 16) {
        l_lds[16 * wave + lr]  = l_part;
        mm_lds[16 * wave + lr] = mm_part;
    }
    __syncthreads();

    if (G == 1) {
        // ---- final epilogue: mem = acc/l ; gated = q_out * (mm/l)
        float* outo = out + (size_t)o * (1024 * NQ);
#pragma unroll
        for (int ng = 0; ng < 4; ng++) {
            const int n  = 16 * ng + lr;
            const int gn = n0 + n;
            if (gn >= NQ) continue;
            const float invl = 1.f / l_lds[n];
            const float gate = mm_lds[n] * invl;
#pragma unroll
            for (int vt = 0; vt < 4; vt++) {
#pragma unroll
                for (int r = 0; r < 4; r++) {
                    const int v = vh * VH_ROWS + 64 * wave + 16 * vt + 4 * q + r;
                    outo[(size_t)v * NQ + gn] = acc[vt][ng][r] * invl;
                    outo[(size_t)(512 + v) * NQ + gn] = q_out[(size_t)v * NQ + gn] * gate;
                }
            }
        }
    } else {
        // ---- partial epilogue: raw acc into out rows [g*512 .. g*512+511]
        float* dst = out + ((size_t)o * 1024 + (size_t)g * 512 + (size_t)vh * VH_ROWS) * NQ;
#pragma unroll
        for (int ng = 0; ng < 4; ng++) {
            const int n  = 16 * ng + lr;
            const int gn = n0 + n;
            if (gn >= NQ) continue;
#pragma unroll
            for (int vt = 0; vt < 4; vt++) {
#pragma unroll
                for (int r = 0; r < 4; r++) {
                    const int v = 64 * wave + 16 * vt + 4 * q + r;
                    dst[(size_t)v * NQ + gn] = acc[vt][ng][r];
                }
            }
        }
        if (vh == 0 && tid < 64) {
            const size_t li = ((size_t)(g * 4 + o) * NTILES + tile) * 64 + tid;
            lw[li] = l_lds[tid];
            mw[li] = mm_lds[tid];
        }
    }
}

// ---------------- combine pass (G=2) ----------------
__global__ void k_combine(const float* __restrict__ q_out, const float* __restrict__ lw,
                          const float* __restrict__ mw, float* __restrict__ out) {
    const int total = O_N * 512 * (NQ / 4);   // float4 elements per half-row set
    float4* outv = reinterpret_cast<float4*>(out);
    const float4* qv = reinterpret_cast<const float4*>(q_out);
    for (int idx = blockIdx.x * blockDim.x + threadIdx.x; idx < total;
         idx += gridDim.x * blockDim.x) {
        const int o  = idx / (512 * 900);
        const int r  = idx - o * 512 * 900;
        const int v  = r / 900;
        const int g4 = r - v * 900;
        const size_t iA = ((size_t)o * 1024 + v) * 900 + g4;
        const size_t iB = ((size_t)o * 1024 + 512 + v) * 900 + g4;
        float4 A = outv[iA];
        float4 B = outv[iB];
        const int tl = g4 >> 4;
        const int wi = (g4 & 15) * 4;
        const size_t l0i = ((size_t)(0 * 4 + o) * NTILES + tl) * 64 + wi;
        const size_t l1i = ((size_t)(1 * 4 + o) * NTILES + tl) * 64 + wi;
        const float4 l0 = *reinterpret_cast<const float4*>(lw + l0i);
        const float4 l1 = *reinterpret_cast<const float4*>(lw + l1i);
        const float4 m0 = *reinterpret_cast<const float4*>(mw + l0i);
        const float4 m1 = *reinterpret_cast<const float4*>(mw + l1i);
        float4 li, mem, gate;
        li.x = 1.f / (l0.x + l1.x); li.y = 1.f / (l0.y + l1.y);
        li.z = 1.f / (l0.z + l1.z); li.w = 1.f / (l0.w + l1.w);
        mem.x = (A.x + B.x) * li.x; mem.y = (A.y + B.y) * li.y;
        mem.z = (A.z + B.z) * li.z; mem.w = (A.w + B.w) * li.w;
        gate.x = (m0.x + m1.x) * li.x; gate.y = (m0.y + m1.y) * li.y;
        gate.z = (m0.z + m1.z) * li.z; gate.w = (m0.w + m1.w) * li.w;
        float4 qo = qv[(size_t)v * 900 + g4];
        outv[iA] = mem;
        float4 gq;
        gq.x = qo.x * gate.x; gq.y = qo.y * gate.y;
        gq.z = qo.z * gate.z; gq.w = qo.w * gate.w;
        outv[iB] = gq;
    }
}

extern "C" void kernel_launch(void* const* d_in, const int* in_sizes, int n_in,
                              void* d_out, int out_size, void* d_ws, size_t ws_size,
                              hipStream_t stream) {
    const float* keys   = (const float*)d_in[0];
    const float* values = (const float*)d_in[1];
    const float* masks  = (const float*)d_in[2];
    const float* q_in   = (const float*)d_in[3];
    const float* q_outp = (const float*)d_in[4];
    float* out = (float*)d_out;

    const size_t K_BYTES  = (size_t)O_N * BANK * D_K * 2;   //  7,372,800
    const size_t V_BYTES  = (size_t)O_N * D_V * BANK * 2;   // 29,491,200
    const size_t LM_FLOATS = (size_t)2 * O_N * NTILES * 64; // per array (G=2)
    const size_t LM_BYTES  = LM_FLOATS * 4 * 2;             // l + mm

    if (ws_size < K_BYTES + V_BYTES) {
        k_zero<<<(out_size + 255) / 256, 256, 0, stream>>>(out, out_size);
        return;
    }
    const int G = (ws_size >= K_BYTES + V_BYTES + LM_BYTES) ? 2 : 1;

    u16* Kt = (u16*)d_ws;
    u16* Vb = (u16*)((char*)d_ws + K_BYTES);
    float* lw = (float*)((char*)d_ws + K_BYTES + V_BYTES);
    float* mw = lw + LM_FLOATS;

    dim3 tb(32, 8);
    dim3 tg(BANK / 32, D_K / 32, O_N);
    k_transpose_bf16<<<tg, tb, 0, stream>>>(keys, Kt);

    const int n4 = O_N * D_V * BANK / 4;
    k_convert_bf16<<<2048, 256, 0, stream>>>(values, Vb, n4);

    k_matcher<<<NTILES * 8 * G, 256, 0, stream>>>(Kt, Vb, masks, q_in, q_outp, out,
                                                  G, lw, mw);
    if (G == 2)
        k_combine<<<2048, 256, 0, stream>>>(q_outp, lw, mw, out);
}